// Round 3
// baseline (211.251 us; speedup 1.0000x reference)
//
#include <hip/hip_runtime.h>
#include <hip/hip_bf16.h>
#include <stdint.h>

// GRU cell, B=32768, IN=256, H=256, CONCAT=512. Fused bf16-MFMA kernel.
// R3: M=32/block (grid 1024, 3 co-resident blocks/CU to hide latency),
// x@whx fused into GEMM1 K-loop (short dependent tail), lazy-z epilogue,
// LDS-transpose prep kernel (coalesced reads AND writes).

typedef float  f32x4  __attribute__((ext_vector_type(4)));
typedef __bf16 bf16x8 __attribute__((ext_vector_type(8)));
typedef short  s16x8  __attribute__((ext_vector_type(8)));

#define B_TOT   32768
#define MT      32              // rows per block
#define WRZ_ELEMS (512*512)     // combined r|z weights, bf16
#define WG_ELEMS  (256*512)     // combined [whx;whh] weights, bf16

__device__ __forceinline__ unsigned short f2b(float f) {
    union { float f; unsigned int u; } v; v.f = f;
    unsigned int r = (v.u + 0x7FFFu + ((v.u >> 16) & 1u)) >> 16;  // RNE
    return (unsigned short)r;
}
__device__ __forceinline__ float b2f(unsigned short b) {
    union { unsigned int u; float f; } v; v.u = ((unsigned int)b) << 16;
    return v.f;
}
__device__ __forceinline__ float sigmoid_f(float x) {
    return 1.0f / (1.0f + __expf(-x));
}
__device__ __forceinline__ float tanh_f(float x) {
    return 1.0f - 2.0f / (__expf(2.0f * x) + 1.0f);
}

// bf16 LDS tile 32x512 (32 KB), XOR-swizzled at 16B (8-elem) granularity.
__device__ __forceinline__ int lds_idx(int row, int col) {
    return row * 512 + ((((col >> 3) ^ (row & 7)) << 3) | (col & 7));
}

// ---------------------------------------------------------------------------
// Prep: fp32 weights -> bf16 MFMA B-fragment order, via LDS transpose.
// Fragment block (nt,ks) is 1 KB: lane l holds B[k=ks*32+(l>>4)*8+j][n=nt*16+(l&15)].
// wrz col space permuted: wave w (=c>>7) owns r-cols [64w,64w+64) at t<64 and
// z-cols [64w,64w+64) at t>=64 (t=c&127). wg k: k<256 -> whx, k>=256 -> whh.
// One block = (nt, kq): 16 cols x 128 k = 4 KB bf16 out, contiguous.
// Reads: 64B segments (half-line). Writes: fully coalesced 16B/lane.
// ---------------------------------------------------------------------------
__global__ void prep_weights(const float* __restrict__ wr,
                             const float* __restrict__ wz,
                             const float* __restrict__ whh,
                             const float* __restrict__ whx,
                             unsigned short* __restrict__ wrz,
                             unsigned short* __restrict__ wg) {
    __shared__ unsigned short lsm[2048];
    const int b = blockIdx.x;
    const bool isRZ = (b < 128);
    const int nt = isRZ ? (b >> 2) : ((b - 128) >> 2);
    const int kq = isRZ ? (b & 3) : ((b - 128) & 3);
    const int k0 = kq * 128;
    const int t = threadIdx.x;

    #pragma unroll
    for (int i = 0; i < 8; ++i) {
        int idx = t + 256 * i;            // 0..2047
        int ct = idx & 15, kk = idx >> 4; // kk 0..127
        int k = k0 + kk;
        float v;
        if (isRZ) {
            int w = nt >> 3, tt = ((nt & 7) << 4) + ct;
            v = (tt < 64) ? wr[k * 256 + w * 64 + tt]
                          : wz[k * 256 + w * 64 + tt - 64];
        } else {
            int n = (nt << 4) + ct;
            v = (k < 256) ? whx[k * 256 + n] : whh[(k - 256) * 256 + n];
        }
        int ksl = kk >> 5, quad = (k >> 3) & 3, j = k & 7;
        lsm[ksl * 512 + ((quad << 4) + ct) * 8 + j] = f2b(v);
    }
    __syncthreads();
    unsigned short* dst = (isRZ ? wrz : wg) + (((nt << 4) + (kq << 2)) << 9);
    *reinterpret_cast<s16x8*>(dst + t * 8) =
        *reinterpret_cast<const s16x8*>(&lsm[t * 8]);
}

// ---------------------------------------------------------------------------
// Fused GRU kernel: 256 threads (4 waves), 32 rows/block, grid 1024.
// Wave w owns output cols [64w, 64w+64) throughout.
// Main K-loop: rz-logits (N=128/wave) + x@whx part of g (ks<8).
// Gates: a = sigmoid(r+br)*h -> LDS h-region; h stashed in r-acc slots,
// z kept as raw logits. Tail: a@whh (ks 8..15). Epilogue: h + z*(g-h).
// ---------------------------------------------------------------------------
__global__ __launch_bounds__(256, 3)
void gru_fused(const float* __restrict__ x, const float* __restrict__ h,
               const unsigned short* __restrict__ wrz,
               const unsigned short* __restrict__ wg,
               const float* __restrict__ br, const float* __restrict__ bz,
               const float* __restrict__ bh, float* __restrict__ out) {
    __shared__ unsigned short xcA[32 * 512];   // 32 KB

    const int tid  = threadIdx.x;
    const int lane = tid & 63;
    const int wv   = tid >> 6;          // wave 0..3
    const int m0   = lane & 15;
    const int q    = lane >> 4;         // quad 0..3
    const int rowBase = blockIdx.x * MT;

    // ---- Stage [x | h] -> LDS bf16 (8 iters, 8 rows per wave)
    #pragma unroll
    for (int it = 0; it < 8; ++it) {
        int row = it * 4 + wv;
        size_t g = (size_t)(rowBase + row) * 256 + lane * 4;
        float4 xv = *reinterpret_cast<const float4*>(x + g);
        float4 hv = *reinterpret_cast<const float4*>(h + g);
        ushort4 xb, hb;
        xb.x = f2b(xv.x); xb.y = f2b(xv.y); xb.z = f2b(xv.z); xb.w = f2b(xv.w);
        hb.x = f2b(hv.x); hb.y = f2b(hv.y); hb.z = f2b(hv.z); hb.w = f2b(hv.w);
        *reinterpret_cast<ushort4*>(&xcA[lds_idx(row, lane * 4)])       = xb;
        *reinterpret_cast<ushort4*>(&xcA[lds_idx(row, 256 + lane * 4)]) = hb;
    }
    __syncthreads();

    // ---- Main K loop: rz logits (jn 0..7) + x@whx into g (ks<8)
    f32x4 rz[8][2];
    f32x4 gac[4][2];
    #pragma unroll
    for (int jn = 0; jn < 8; ++jn)
        #pragma unroll
        for (int mt = 0; mt < 2; ++mt)
            rz[jn][mt] = (f32x4){0.f, 0.f, 0.f, 0.f};
    #pragma unroll
    for (int j = 0; j < 4; ++j)
        #pragma unroll
        for (int mt = 0; mt < 2; ++mt)
            gac[j][mt] = (f32x4){0.f, 0.f, 0.f, 0.f};

    const unsigned short* wrzW = wrz + (size_t)wv * 8 * 16 * 512;
    const unsigned short* wgW  = wg  + (size_t)wv * 4 * 16 * 512;

    for (int ks = 0; ks < 8; ++ks) {       // k < 256: rz + whx
        bf16x8 afr[2];
        #pragma unroll
        for (int mt = 0; mt < 2; ++mt) {
            s16x8 raw = *reinterpret_cast<const s16x8*>(
                &xcA[lds_idx(mt * 16 + m0, ks * 32 + q * 8)]);
            afr[mt] = __builtin_bit_cast(bf16x8, raw);
        }
        #pragma unroll
        for (int jn = 0; jn < 8; ++jn) {
            s16x8 braw = *reinterpret_cast<const s16x8*>(
                wrzW + (((jn << 4) + ks) << 9) + lane * 8);
            bf16x8 bfr = __builtin_bit_cast(bf16x8, braw);
            #pragma unroll
            for (int mt = 0; mt < 2; ++mt)
                rz[jn][mt] = __builtin_amdgcn_mfma_f32_16x16x32_bf16(
                    afr[mt], bfr, rz[jn][mt], 0, 0, 0);
        }
        #pragma unroll
        for (int j = 0; j < 4; ++j) {
            s16x8 braw = *reinterpret_cast<const s16x8*>(
                wgW + (((j << 4) + ks) << 9) + lane * 8);
            bf16x8 bfr = __builtin_bit_cast(bf16x8, braw);
            #pragma unroll
            for (int mt = 0; mt < 2; ++mt)
                gac[j][mt] = __builtin_amdgcn_mfma_f32_16x16x32_bf16(
                    afr[mt], bfr, gac[j][mt], 0, 0, 0);
        }
    }
    for (int ks = 8; ks < 16; ++ks) {      // k >= 256: rz only
        bf16x8 afr[2];
        #pragma unroll
        for (int mt = 0; mt < 2; ++mt) {
            s16x8 raw = *reinterpret_cast<const s16x8*>(
                &xcA[lds_idx(mt * 16 + m0, ks * 32 + q * 8)]);
            afr[mt] = __builtin_bit_cast(bf16x8, raw);
        }
        #pragma unroll
        for (int jn = 0; jn < 8; ++jn) {
            s16x8 braw = *reinterpret_cast<const s16x8*>(
                wrzW + (((jn << 4) + ks) << 9) + lane * 8);
            bf16x8 bfr = __builtin_bit_cast(bf16x8, braw);
            #pragma unroll
            for (int mt = 0; mt < 2; ++mt)
                rz[jn][mt] = __builtin_amdgcn_mfma_f32_16x16x32_bf16(
                    afr[mt], bfr, rz[jn][mt], 0, 0, 0);
        }
    }
    __syncthreads();   // GEMM1 LDS reads done before h-region overwrite

    // ---- Gates: a = sigmoid(r+br)*h -> LDS; stash h in r slots
    #pragma unroll
    for (int j = 0; j < 4; ++j) {
        int col = 64 * wv + j * 16 + m0;
        float brv = br[col];
        #pragma unroll
        for (int mt = 0; mt < 2; ++mt) {
            #pragma unroll
            for (int rg = 0; rg < 4; ++rg) {
                int row = mt * 16 + q * 4 + rg;
                int hid = lds_idx(row, 256 + col);
                float hval = b2f(xcA[hid]);
                float rs = sigmoid_f(rz[j][mt][rg] + brv);
                xcA[hid] = f2b(rs * hval);   // a = r*h
                rz[j][mt][rg] = hval;        // stash h (r slot now dead)
            }
        }
    }
    __syncthreads();   // a visible to all waves

    // ---- Tail: g += a @ whh (ks 8..15)
    for (int ks = 8; ks < 16; ++ks) {
        bf16x8 afr[2];
        #pragma unroll
        for (int mt = 0; mt < 2; ++mt) {
            s16x8 raw = *reinterpret_cast<const s16x8*>(
                &xcA[lds_idx(mt * 16 + m0, ks * 32 + q * 8)]);
            afr[mt] = __builtin_bit_cast(bf16x8, raw);
        }
        #pragma unroll
        for (int j = 0; j < 4; ++j) {
            s16x8 braw = *reinterpret_cast<const s16x8*>(
                wgW + (((j << 4) + ks) << 9) + lane * 8);
            bf16x8 bfr = __builtin_bit_cast(bf16x8, braw);
            #pragma unroll
            for (int mt = 0; mt < 2; ++mt)
                gac[j][mt] = __builtin_amdgcn_mfma_f32_16x16x32_bf16(
                    afr[mt], bfr, gac[j][mt], 0, 0, 0);
        }
    }

    // ---- Epilogue: h_out = h + z*(g - h)   (z = sigmoid(zlogit+bz))
    #pragma unroll
    for (int j = 0; j < 4; ++j) {
        int col = 64 * wv + j * 16 + m0;
        float bzv = bz[col];
        float bhv = bh[col];
        #pragma unroll
        for (int mt = 0; mt < 2; ++mt) {
            #pragma unroll
            for (int rg = 0; rg < 4; ++rg) {
                int row = mt * 16 + q * 4 + rg;
                float zs = sigmoid_f(rz[4 + j][mt][rg] + bzv);
                float gv = tanh_f(gac[j][mt][rg] + bhv);
                float hval = rz[j][mt][rg];
                out[(size_t)(rowBase + row) * 256 + col] = hval + zs * (gv - hval);
            }
        }
    }
}

extern "C" void kernel_launch(void* const* d_in, const int* in_sizes, int n_in,
                              void* d_out, int out_size, void* d_ws, size_t ws_size,
                              hipStream_t stream) {
    const float* x   = (const float*)d_in[0];
    const float* h   = (const float*)d_in[1];
    const float* wr  = (const float*)d_in[2];
    const float* wz  = (const float*)d_in[3];
    const float* whh = (const float*)d_in[4];
    const float* whx = (const float*)d_in[5];
    const float* br  = (const float*)d_in[6];
    const float* bz  = (const float*)d_in[7];
    const float* bh  = (const float*)d_in[8];
    float* out = (float*)d_out;

    unsigned short* wrz = (unsigned short*)d_ws;       // 512 KB
    unsigned short* wg  = wrz + WRZ_ELEMS;             // 256 KB

    prep_weights<<<192, 256, 0, stream>>>(wr, wz, whh, whx, wrz, wg);
    gru_fused<<<B_TOT / MT, 256, 0, stream>>>(x, h, wrz, wg, br, bz, bh, out);
}

// Round 4
// 156.094 us; speedup vs baseline: 1.3534x; 1.3534x over previous
//
#include <hip/hip_runtime.h>
#include <hip/hip_bf16.h>
#include <stdint.h>

// GRU cell, B=32768, IN=256, H=256, CONCAT=512. Fused bf16-MFMA kernel.
// R4: M=64, 8 waves (mt=4 intensity), explicit 1-deep B-fragment prefetch
// rotation (compiler won't pipeline on its own: R2/R3 evidence), ks-major
// weight layout (per-wave per-ks = contiguous 4KB slab), whx fused into main
// K-loop, lazy-z + h-stash epilogue, direct stores.

typedef float  f32x4  __attribute__((ext_vector_type(4)));
typedef __bf16 bf16x8 __attribute__((ext_vector_type(8)));
typedef short  s16x8  __attribute__((ext_vector_type(8)));

#define B_TOT   32768
#define MT      64
#define WRZ_ELEMS (512*512)
#define WG_ELEMS  (256*512)

__device__ __forceinline__ unsigned short f2b(float f) {
    union { float f; unsigned int u; } v; v.f = f;
    unsigned int r = (v.u + 0x7FFFu + ((v.u >> 16) & 1u)) >> 16;  // RNE
    return (unsigned short)r;
}
__device__ __forceinline__ float b2f(unsigned short b) {
    union { unsigned int u; float f; } v; v.u = ((unsigned int)b) << 16;
    return v.f;
}
__device__ __forceinline__ float sigmoid_f(float x) {
    return 1.0f / (1.0f + __expf(-x));
}
__device__ __forceinline__ float tanh_f(float x) {
    return 1.0f - 2.0f / (__expf(2.0f * x) + 1.0f);
}

// bf16 LDS tile 64x512 (64 KB), XOR-swizzled at 16B (8-elem) granularity.
__device__ __forceinline__ int lds_idx(int row, int col) {
    return row * 512 + ((((col >> 3) ^ (row & 7)) << 3) | (col & 7));
}

// ---------------------------------------------------------------------------
// Prep: fp32 -> bf16 in ks-major per-wave fragment pages.
// wrz page (wave w): [ks 0..15][jn 0..3][512 shorts]; jn 0,1 = r-cols
// 32w+jn*16+(l&15); jn 2,3 = z-cols 32w+(jn-2)*16+(l&15);
// lane l holds k = ks*32+(l>>4)*8+jj, jj=0..7.
// wg page (wave w): [ks 0..15][j 0..1][512]; col 32w+j*16+(l&15);
// k<256 -> whx, k>=256 -> whh.
// Writes: fully coalesced 16 B/thread. Reads: 64 B gather segments.
// ---------------------------------------------------------------------------
__global__ void prep_weights(const float* __restrict__ wr,
                             const float* __restrict__ wz,
                             const float* __restrict__ whh,
                             const float* __restrict__ whx,
                             unsigned short* __restrict__ wrz,
                             unsigned short* __restrict__ wg) {
    const int b = blockIdx.x;
    const int t = threadIdx.x;
    union { s16x8 v; unsigned short u[8]; } tmp;

    if (b < 128) {                       // wrz: block = (w, ks)
        int w = b >> 4, ks = b & 15;
        int jn = t >> 6, l = t & 63;
        int kbase = ks * 32 + ((l >> 4) << 3);
        int n = 32 * w + ((jn & 1) << 4) + (l & 15);
        const float* src = (jn < 2) ? wr : wz;
        #pragma unroll
        for (int jj = 0; jj < 8; ++jj)
            tmp.u[jj] = f2b(src[(kbase + jj) * 256 + n]);
        *reinterpret_cast<s16x8*>(wrz + (size_t)w * 32768 + ks * 2048 + t * 8) = tmp.v;
    } else {                             // wg: block = (w, ks-pair)
        int b2 = b - 128;
        int w = b2 >> 3, ksp = b2 & 7;
        int ksl = t >> 7, j = (t >> 6) & 1, l = t & 63;
        int ks = ksp * 2 + ksl;
        int kbase = ks * 32 + ((l >> 4) << 3);
        int n = 32 * w + (j << 4) + (l & 15);
        #pragma unroll
        for (int jj = 0; jj < 8; ++jj) {
            int k = kbase + jj;
            tmp.u[jj] = f2b((k < 256) ? whx[k * 256 + n] : whh[(k - 256) * 256 + n]);
        }
        *reinterpret_cast<s16x8*>(wg + (size_t)w * 16384 + ksp * 2048 + t * 8) = tmp.v;
    }
}

// ---------------------------------------------------------------------------
// Fused GRU: 512 threads (8 waves), 64 rows/block, grid 512.
// Wave w owns r/z cols [32w,32w+32) and g cols [32w,32w+32).
// Main loop: rz (16 MFMA/ks) + whx (8 MFMA/ks, ks<8), B rz-fragments
// rotated 1-deep. Gates: a=sigmoid(r+br)*h -> x-region of LDS; h stashed in
// r-acc. Tail: g += a@whh (8 ks, rotated). Epilogue: h + z*(tanh(g+bh)-h).
// ---------------------------------------------------------------------------
__global__ __launch_bounds__(512, 3)
void gru_fused(const float* __restrict__ x, const float* __restrict__ h,
               const unsigned short* __restrict__ wrz,
               const unsigned short* __restrict__ wg,
               const float* __restrict__ br, const float* __restrict__ bz,
               const float* __restrict__ bh, float* __restrict__ out) {
    __shared__ unsigned short xcA[64 * 512];   // 64 KB

    const int tid  = threadIdx.x;
    const int lane = tid & 63;
    const int wv   = tid >> 6;          // wave 0..7
    const int m0   = lane & 15;
    const int q    = lane >> 4;
    const int rowBase = blockIdx.x * MT;

    // Bias registers (needed later; load early, off the critical path)
    float brv[2], bzv[2], bhv[2];
    #pragma unroll
    for (int j = 0; j < 2; ++j) {
        int col = 32 * wv + j * 16 + m0;
        brv[j] = br[col]; bzv[j] = bz[col]; bhv[j] = bh[col];
    }

    // ---- Stage [x | h] -> LDS bf16 (8 rows/wave)
    #pragma unroll
    for (int it = 0; it < 8; ++it) {
        int row = it * 8 + wv;
        size_t g = (size_t)(rowBase + row) * 256 + lane * 4;
        float4 xv = *reinterpret_cast<const float4*>(x + g);
        float4 hv = *reinterpret_cast<const float4*>(h + g);
        ushort4 xb, hb;
        xb.x = f2b(xv.x); xb.y = f2b(xv.y); xb.z = f2b(xv.z); xb.w = f2b(xv.w);
        hb.x = f2b(hv.x); hb.y = f2b(hv.y); hb.z = f2b(hv.z); hb.w = f2b(hv.w);
        *reinterpret_cast<ushort4*>(&xcA[lds_idx(row, lane * 4)])       = xb;
        *reinterpret_cast<ushort4*>(&xcA[lds_idx(row, 256 + lane * 4)]) = hb;
    }

    const unsigned short* wrzP = wrz + (size_t)wv * 32768;
    const unsigned short* wgP  = wg  + (size_t)wv * 16384;

    // Prefetch ks=0 rz B-fragments (no LDS dependency -> before barrier)
    s16x8 bR[4], nR[4];
    #pragma unroll
    for (int jn = 0; jn < 4; ++jn)
        bR[jn] = *reinterpret_cast<const s16x8*>(wrzP + jn * 512 + lane * 8);

    __syncthreads();

    f32x4 rz[4][4];     // [jn][mt]: jn 0,1 = r; jn 2,3 = z
    f32x4 gac[2][4];    // [j][mt]: g accumulator
    #pragma unroll
    for (int jn = 0; jn < 4; ++jn)
        #pragma unroll
        for (int mt = 0; mt < 4; ++mt)
            rz[jn][mt] = (f32x4){0.f, 0.f, 0.f, 0.f};
    #pragma unroll
    for (int j = 0; j < 2; ++j)
        #pragma unroll
        for (int mt = 0; mt < 4; ++mt)
            gac[j][mt] = (f32x4){0.f, 0.f, 0.f, 0.f};

    // ---- Main loop part 1: ks 0..7 (rz + whx)
    for (int ks = 0; ks < 8; ++ks) {
        bf16x8 afr[4];
        #pragma unroll
        for (int mt = 0; mt < 4; ++mt) {
            s16x8 raw = *reinterpret_cast<const s16x8*>(
                &xcA[lds_idx(mt * 16 + m0, ks * 32 + q * 8)]);
            afr[mt] = __builtin_bit_cast(bf16x8, raw);
        }
        #pragma unroll
        for (int jn = 0; jn < 4; ++jn)      // prefetch ks+1 rz B
            nR[jn] = *reinterpret_cast<const s16x8*>(
                wrzP + (ks + 1) * 2048 + jn * 512 + lane * 8);
        s16x8 bG0 = *reinterpret_cast<const s16x8*>(wgP + ks * 1024 + lane * 8);
        s16x8 bG1 = *reinterpret_cast<const s16x8*>(wgP + ks * 1024 + 512 + lane * 8);
        #pragma unroll
        for (int jn = 0; jn < 4; ++jn) {
            bf16x8 bfr = __builtin_bit_cast(bf16x8, bR[jn]);
            #pragma unroll
            for (int mt = 0; mt < 4; ++mt)
                rz[jn][mt] = __builtin_amdgcn_mfma_f32_16x16x32_bf16(
                    afr[mt], bfr, rz[jn][mt], 0, 0, 0);
        }
        {
            bf16x8 g0 = __builtin_bit_cast(bf16x8, bG0);
            bf16x8 g1 = __builtin_bit_cast(bf16x8, bG1);
            #pragma unroll
            for (int mt = 0; mt < 4; ++mt)
                gac[0][mt] = __builtin_amdgcn_mfma_f32_16x16x32_bf16(
                    afr[mt], g0, gac[0][mt], 0, 0, 0);
            #pragma unroll
            for (int mt = 0; mt < 4; ++mt)
                gac[1][mt] = __builtin_amdgcn_mfma_f32_16x16x32_bf16(
                    afr[mt], g1, gac[1][mt], 0, 0, 0);
        }
        #pragma unroll
        for (int jn = 0; jn < 4; ++jn) bR[jn] = nR[jn];
    }
    // ---- Main loop part 2: ks 8..15 (rz only)
    for (int ks = 8; ks < 16; ++ks) {
        bf16x8 afr[4];
        #pragma unroll
        for (int mt = 0; mt < 4; ++mt) {
            s16x8 raw = *reinterpret_cast<const s16x8*>(
                &xcA[lds_idx(mt * 16 + m0, ks * 32 + q * 8)]);
            afr[mt] = __builtin_bit_cast(bf16x8, raw);
        }
        int ksn = (ks + 1) & 15;            // ks=15 wraps (harmless dummy)
        #pragma unroll
        for (int jn = 0; jn < 4; ++jn)
            nR[jn] = *reinterpret_cast<const s16x8*>(
                wrzP + ksn * 2048 + jn * 512 + lane * 8);
        #pragma unroll
        for (int jn = 0; jn < 4; ++jn) {
            bf16x8 bfr = __builtin_bit_cast(bf16x8, bR[jn]);
            #pragma unroll
            for (int mt = 0; mt < 4; ++mt)
                rz[jn][mt] = __builtin_amdgcn_mfma_f32_16x16x32_bf16(
                    afr[mt], bfr, rz[jn][mt], 0, 0, 0);
        }
        #pragma unroll
        for (int jn = 0; jn < 4; ++jn) bR[jn] = nR[jn];
    }
    __syncthreads();   // all LDS A-reads done before x-region overwrite

    // Prefetch first tail B (whh, ks=8) before gates VALU work
    s16x8 tG[2], nT[2];
    #pragma unroll
    for (int j = 0; j < 2; ++j)
        tG[j] = *reinterpret_cast<const s16x8*>(
            wgP + 8 * 1024 + j * 512 + lane * 8);

    // ---- Gates: a = sigmoid(r+br)*h -> LDS x-region; stash h in r-acc
    #pragma unroll
    for (int j = 0; j < 2; ++j) {
        int col = 32 * wv + j * 16 + m0;
        #pragma unroll
        for (int mt = 0; mt < 4; ++mt) {
            #pragma unroll
            for (int rg = 0; rg < 4; ++rg) {
                int row = mt * 16 + q * 4 + rg;
                float hval = b2f(xcA[lds_idx(row, 256 + col)]);
                float rs = sigmoid_f(rz[j][mt][rg] + brv[j]);
                xcA[lds_idx(row, col)] = f2b(rs * hval);   // a over x-region
                rz[j][mt][rg] = hval;                      // stash h
            }
        }
    }
    __syncthreads();   // a visible to all waves

    // ---- Tail: g += a @ whh (tail kt 0..7 reads x-region; B = wg ks 8..15)
    for (int kt = 0; kt < 8; ++kt) {
        bf16x8 afr[4];
        #pragma unroll
        for (int mt = 0; mt < 4; ++mt) {
            s16x8 raw = *reinterpret_cast<const s16x8*>(
                &xcA[lds_idx(mt * 16 + m0, kt * 32 + q * 8)]);
            afr[mt] = __builtin_bit_cast(bf16x8, raw);
        }
        int ktn = 8 + ((kt + 1) & 7);
        #pragma unroll
        for (int j = 0; j < 2; ++j)
            nT[j] = *reinterpret_cast<const s16x8*>(
                wgP + ktn * 1024 + j * 512 + lane * 8);
        #pragma unroll
        for (int j = 0; j < 2; ++j) {
            bf16x8 bfr = __builtin_bit_cast(bf16x8, tG[j]);
            #pragma unroll
            for (int mt = 0; mt < 4; ++mt)
                gac[j][mt] = __builtin_amdgcn_mfma_f32_16x16x32_bf16(
                    afr[mt], bfr, gac[j][mt], 0, 0, 0);
        }
        #pragma unroll
        for (int j = 0; j < 2; ++j) tG[j] = nT[j];
    }

    // ---- Epilogue: h_out = h + z*(tanh(g+bh) - h), z = sigmoid(zlogit+bz)
    #pragma unroll
    for (int j = 0; j < 2; ++j) {
        int col = 32 * wv + j * 16 + m0;
        #pragma unroll
        for (int mt = 0; mt < 4; ++mt) {
            #pragma unroll
            for (int rg = 0; rg < 4; ++rg) {
                int row = mt * 16 + q * 4 + rg;
                float zs = sigmoid_f(rz[2 + j][mt][rg] + bzv[j]);
                float gv = tanh_f(gac[j][mt][rg] + bhv[j]);
                float hval = rz[j][mt][rg];
                out[(size_t)(rowBase + row) * 256 + col] = hval + zs * (gv - hval);
            }
        }
    }
}

extern "C" void kernel_launch(void* const* d_in, const int* in_sizes, int n_in,
                              void* d_out, int out_size, void* d_ws, size_t ws_size,
                              hipStream_t stream) {
    const float* x   = (const float*)d_in[0];
    const float* h   = (const float*)d_in[1];
    const float* wr  = (const float*)d_in[2];
    const float* wz  = (const float*)d_in[3];
    const float* whh = (const float*)d_in[4];
    const float* whx = (const float*)d_in[5];
    const float* br  = (const float*)d_in[6];
    const float* bz  = (const float*)d_in[7];
    const float* bh  = (const float*)d_in[8];
    float* out = (float*)d_out;

    unsigned short* wrz = (unsigned short*)d_ws;       // 512 KB
    unsigned short* wg  = wrz + WRZ_ELEMS;             // 256 KB

    prep_weights<<<192, 256, 0, stream>>>(wr, wz, whh, whx, wrz, wg);
    gru_fused<<<B_TOT / MT, 512, 0, stream>>>(x, h, wrz, wg, br, bz, bh, out);
}

// Round 5
// 156.047 us; speedup vs baseline: 1.3538x; 1.0003x over previous
//
#include <hip/hip_runtime.h>
#include <hip/hip_bf16.h>
#include <stdint.h>

// GRU cell, B=32768, IN=256, H=256, CONCAT=512. Fused bf16-MFMA kernel.
// R5: occupancy is pinned at 8 waves/CU by the 96-reg accumulator (R4
// post-mortem), so spend free registers on a 2-ks double-buffered B-fragment
// pipeline (~230 MFMA cyc cover per wave, ~460 with 2 waves/SIMD > ~300 cyc
// L2 latency). HW packed bf16 cvt in staging. Prep unchanged from R4.

typedef float  f32x4  __attribute__((ext_vector_type(4)));
typedef __bf16 bf16x8 __attribute__((ext_vector_type(8)));
typedef short  s16x8  __attribute__((ext_vector_type(8)));

#define B_TOT   32768
#define MT      64
#define WRZ_ELEMS (512*512)
#define WG_ELEMS  (256*512)

__device__ __forceinline__ unsigned short f2b(float f) {
    union { float f; unsigned int u; } v; v.f = f;
    unsigned int r = (v.u + 0x7FFFu + ((v.u >> 16) & 1u)) >> 16;  // RNE
    return (unsigned short)r;
}
__device__ __forceinline__ float b2f(unsigned short b) {
    union { unsigned int u; float f; } v; v.u = ((unsigned int)b) << 16;
    return v.f;
}
__device__ __forceinline__ ushort2 pk2(float a, float b) {   // v_cvt_pk_bf16_f32
    __hip_bfloat162 t = __float22bfloat162_rn(make_float2(a, b));
    union { __hip_bfloat162 h; ushort2 u; } c; c.h = t; return c.u;
}
__device__ __forceinline__ float sigmoid_f(float x) {
    return 1.0f / (1.0f + __expf(-x));
}
__device__ __forceinline__ float tanh_f(float x) {
    return 1.0f - 2.0f / (__expf(2.0f * x) + 1.0f);
}

// bf16 LDS tile 64x512 (64 KB), XOR-swizzled at 16B (8-elem) granularity.
__device__ __forceinline__ int lds_idx(int row, int col) {
    return row * 512 + ((((col >> 3) ^ (row & 7)) << 3) | (col & 7));
}

// ---------------------------------------------------------------------------
// Prep (unchanged from R4): fp32 -> bf16 ks-major per-wave fragment pages.
// wrz page (wave w): [ks 0..15][jn 0..3][512]; jn 0,1 r-cols, jn 2,3 z-cols.
// wg  page (wave w): [ks 0..15][j 0..1][512]; k<256 whx, k>=256 whh.
// ---------------------------------------------------------------------------
__global__ void prep_weights(const float* __restrict__ wr,
                             const float* __restrict__ wz,
                             const float* __restrict__ whh,
                             const float* __restrict__ whx,
                             unsigned short* __restrict__ wrz,
                             unsigned short* __restrict__ wg) {
    const int b = blockIdx.x;
    const int t = threadIdx.x;
    union { s16x8 v; unsigned short u[8]; } tmp;

    if (b < 128) {                       // wrz: block = (w, ks)
        int w = b >> 4, ks = b & 15;
        int jn = t >> 6, l = t & 63;
        int kbase = ks * 32 + ((l >> 4) << 3);
        int n = 32 * w + ((jn & 1) << 4) + (l & 15);
        const float* src = (jn < 2) ? wr : wz;
        #pragma unroll
        for (int jj = 0; jj < 8; ++jj)
            tmp.u[jj] = f2b(src[(kbase + jj) * 256 + n]);
        *reinterpret_cast<s16x8*>(wrz + (size_t)w * 32768 + ks * 2048 + t * 8) = tmp.v;
    } else {                             // wg: block = (w, ks-pair)
        int b2 = b - 128;
        int w = b2 >> 3, ksp = b2 & 7;
        int ksl = t >> 7, j = (t >> 6) & 1, l = t & 63;
        int ks = ksp * 2 + ksl;
        int kbase = ks * 32 + ((l >> 4) << 3);
        int n = 32 * w + (j << 4) + (l & 15);
        #pragma unroll
        for (int jj = 0; jj < 8; ++jj) {
            int k = kbase + jj;
            tmp.u[jj] = f2b((k < 256) ? whx[k * 256 + n] : whh[(k - 256) * 256 + n]);
        }
        *reinterpret_cast<s16x8*>(wg + (size_t)w * 16384 + ksp * 2048 + t * 8) = tmp.v;
    }
}

// ---------------------------------------------------------------------------
// Fused GRU: 512 threads (8 waves), 64 rows/block, grid 512.
// Wave w owns r/z/g cols [32w,32w+32). Main loop: 8 groups of 2 ks, B
// double-buffered (group g+1 loads issued before group g MFMAs retire).
// Gates: a=sigmoid(r+br)*h -> x-region; h stashed in r-acc. Tail: 4 groups
// of 2 kt, double-buffered. Epilogue: h + z*(tanh(g+bh)-h).
// ---------------------------------------------------------------------------
__global__ __launch_bounds__(512, 2)
void gru_fused(const float* __restrict__ x, const float* __restrict__ h,
               const unsigned short* __restrict__ wrz,
               const unsigned short* __restrict__ wg,
               const float* __restrict__ br, const float* __restrict__ bz,
               const float* __restrict__ bh, float* __restrict__ out) {
    __shared__ unsigned short xcA[64 * 512];   // 64 KB

    const int tid  = threadIdx.x;
    const int lane = tid & 63;
    const int wv   = tid >> 6;          // wave 0..7
    const int m0   = lane & 15;
    const int q    = lane >> 4;
    const int rowBase = blockIdx.x * MT;

    float brv[2], bzv[2], bhv[2];
    #pragma unroll
    for (int j = 0; j < 2; ++j) {
        int col = 32 * wv + j * 16 + m0;
        brv[j] = br[col]; bzv[j] = bz[col]; bhv[j] = bh[col];
    }

    // ---- Stage [x | h] -> LDS bf16 (packed HW cvt)
    #pragma unroll
    for (int it = 0; it < 8; ++it) {
        int row = it * 8 + wv;
        size_t g = (size_t)(rowBase + row) * 256 + lane * 4;
        float4 xv = *reinterpret_cast<const float4*>(x + g);
        float4 hv = *reinterpret_cast<const float4*>(h + g);
        ushort2 x0 = pk2(xv.x, xv.y), x1 = pk2(xv.z, xv.w);
        ushort2 h0 = pk2(hv.x, hv.y), h1 = pk2(hv.z, hv.w);
        ushort4 xb = make_ushort4(x0.x, x0.y, x1.x, x1.y);
        ushort4 hb = make_ushort4(h0.x, h0.y, h1.x, h1.y);
        *reinterpret_cast<ushort4*>(&xcA[lds_idx(row, lane * 4)])       = xb;
        *reinterpret_cast<ushort4*>(&xcA[lds_idx(row, 256 + lane * 4)]) = hb;
    }

    const unsigned short* wrzP = wrz + (size_t)wv * 32768;
    const unsigned short* wgP  = wg  + (size_t)wv * 16384;

    // ---- Preload B group 0 (ks 0,1: 4 rz + 2 g frags per ks)
    s16x8 Bb[2][12];
    #pragma unroll
    for (int k2 = 0; k2 < 2; ++k2) {
        #pragma unroll
        for (int jn = 0; jn < 4; ++jn)
            Bb[0][k2 * 6 + jn] = *reinterpret_cast<const s16x8*>(
                wrzP + k2 * 2048 + jn * 512 + lane * 8);
        #pragma unroll
        for (int j = 0; j < 2; ++j)
            Bb[0][k2 * 6 + 4 + j] = *reinterpret_cast<const s16x8*>(
                wgP + k2 * 1024 + j * 512 + lane * 8);
    }

    __syncthreads();

    f32x4 rz[4][4];     // jn 0,1 = r; jn 2,3 = z
    f32x4 gac[2][4];
    #pragma unroll
    for (int jn = 0; jn < 4; ++jn)
        #pragma unroll
        for (int mt = 0; mt < 4; ++mt)
            rz[jn][mt] = (f32x4){0.f, 0.f, 0.f, 0.f};
    #pragma unroll
    for (int j = 0; j < 2; ++j)
        #pragma unroll
        for (int mt = 0; mt < 4; ++mt)
            gac[j][mt] = (f32x4){0.f, 0.f, 0.f, 0.f};

    // ---- Main loop: 8 groups x 2 ks. grp<4: rz+g, grp>=4: rz only.
    #pragma unroll
    for (int grp = 0; grp < 8; ++grp) {
        const int cur = grp & 1, nxt = cur ^ 1;
        if (grp < 7) {
            int gn = grp + 1;
            #pragma unroll
            for (int k2 = 0; k2 < 2; ++k2) {
                int ks = gn * 2 + k2;
                #pragma unroll
                for (int jn = 0; jn < 4; ++jn)
                    Bb[nxt][k2 * 6 + jn] = *reinterpret_cast<const s16x8*>(
                        wrzP + ks * 2048 + jn * 512 + lane * 8);
                if (gn < 4) {
                    #pragma unroll
                    for (int j = 0; j < 2; ++j)
                        Bb[nxt][k2 * 6 + 4 + j] = *reinterpret_cast<const s16x8*>(
                            wgP + ks * 1024 + j * 512 + lane * 8);
                }
            }
        }
        #pragma unroll
        for (int k2 = 0; k2 < 2; ++k2) {
            int ks = grp * 2 + k2;
            bf16x8 afr[4];
            #pragma unroll
            for (int mt = 0; mt < 4; ++mt) {
                int row = mt * 16 + m0;
                int idx = row * 512 + ((((ks << 2) | q) ^ (row & 7)) << 3);
                afr[mt] = __builtin_bit_cast(bf16x8,
                    *reinterpret_cast<const s16x8*>(&xcA[idx]));
            }
            #pragma unroll
            for (int jn = 0; jn < 4; ++jn) {
                bf16x8 bf = __builtin_bit_cast(bf16x8, Bb[cur][k2 * 6 + jn]);
                #pragma unroll
                for (int mt = 0; mt < 4; ++mt)
                    rz[jn][mt] = __builtin_amdgcn_mfma_f32_16x16x32_bf16(
                        afr[mt], bf, rz[jn][mt], 0, 0, 0);
            }
            if (grp < 4) {
                #pragma unroll
                for (int j = 0; j < 2; ++j) {
                    bf16x8 bf = __builtin_bit_cast(bf16x8, Bb[cur][k2 * 6 + 4 + j]);
                    #pragma unroll
                    for (int mt = 0; mt < 4; ++mt)
                        gac[j][mt] = __builtin_amdgcn_mfma_f32_16x16x32_bf16(
                            afr[mt], bf, gac[j][mt], 0, 0, 0);
                }
            }
        }
    }
    __syncthreads();   // all LDS A-reads done before x-region overwrite

    // ---- Preload tail group 0 (whh pages 8,9)
    s16x8 Tb[2][4];
    #pragma unroll
    for (int k2 = 0; k2 < 2; ++k2)
        #pragma unroll
        for (int j = 0; j < 2; ++j)
            Tb[0][k2 * 2 + j] = *reinterpret_cast<const s16x8*>(
                wgP + (8 + k2) * 1024 + j * 512 + lane * 8);

    // ---- Gates: a = sigmoid(r+br)*h -> LDS x-region; stash h in r-acc
    #pragma unroll
    for (int j = 0; j < 2; ++j) {
        int col = 32 * wv + j * 16 + m0;
        #pragma unroll
        for (int mt = 0; mt < 4; ++mt) {
            #pragma unroll
            for (int rg = 0; rg < 4; ++rg) {
                int row = mt * 16 + q * 4 + rg;
                float hval = b2f(xcA[lds_idx(row, 256 + col)]);
                float rs = sigmoid_f(rz[j][mt][rg] + brv[j]);
                xcA[lds_idx(row, col)] = f2b(rs * hval);
                rz[j][mt][rg] = hval;
            }
        }
    }
    __syncthreads();   // a visible to all waves

    // ---- Tail: g += a @ whh, 4 groups x 2 kt, double-buffered
    #pragma unroll
    for (int tg = 0; tg < 4; ++tg) {
        const int cur = tg & 1, nxt = cur ^ 1;
        if (tg < 3) {
            #pragma unroll
            for (int k2 = 0; k2 < 2; ++k2)
                #pragma unroll
                for (int j = 0; j < 2; ++j)
                    Tb[nxt][k2 * 2 + j] = *reinterpret_cast<const s16x8*>(
                        wgP + (10 + tg * 2 + k2) * 1024 + j * 512 + lane * 8);
        }
        #pragma unroll
        for (int k2 = 0; k2 < 2; ++k2) {
            int kt = tg * 2 + k2;
            bf16x8 afr[4];
            #pragma unroll
            for (int mt = 0; mt < 4; ++mt) {
                int row = mt * 16 + m0;
                int idx = row * 512 + ((((kt << 2) | q) ^ (row & 7)) << 3);
                afr[mt] = __builtin_bit_cast(bf16x8,
                    *reinterpret_cast<const s16x8*>(&xcA[idx]));
            }
            #pragma unroll
            for (int j = 0; j < 2; ++j) {
                bf16x8 bf = __builtin_bit_cast(bf16x8, Tb[cur][k2 * 2 + j]);
                #pragma unroll
                for (int mt = 0; mt < 4; ++mt)
                    gac[j][mt] = __builtin_amdgcn_mfma_f32_16x16x32_bf16(
                        afr[mt], bf, gac[j][mt], 0, 0, 0);
            }
        }
    }

    // ---- Epilogue: h_out = h + z*(tanh(g+bh) - h)
    #pragma unroll
    for (int j = 0; j < 2; ++j) {
        int col = 32 * wv + j * 16 + m0;
        #pragma unroll
        for (int mt = 0; mt < 4; ++mt) {
            #pragma unroll
            for (int rg = 0; rg < 4; ++rg) {
                int row = mt * 16 + q * 4 + rg;
                float zs = sigmoid_f(rz[2 + j][mt][rg] + bzv[j]);
                float gv = tanh_f(gac[j][mt][rg] + bhv[j]);
                float hval = rz[j][mt][rg];
                out[(size_t)(rowBase + row) * 256 + col] = hval + zs * (gv - hval);
            }
        }
    }
}

extern "C" void kernel_launch(void* const* d_in, const int* in_sizes, int n_in,
                              void* d_out, int out_size, void* d_ws, size_t ws_size,
                              hipStream_t stream) {
    const float* x   = (const float*)d_in[0];
    const float* h   = (const float*)d_in[1];
    const float* wr  = (const float*)d_in[2];
    const float* wz  = (const float*)d_in[3];
    const float* whh = (const float*)d_in[4];
    const float* whx = (const float*)d_in[5];
    const float* br  = (const float*)d_in[6];
    const float* bz  = (const float*)d_in[7];
    const float* bh  = (const float*)d_in[8];
    float* out = (float*)d_out;

    unsigned short* wrz = (unsigned short*)d_ws;       // 512 KB
    unsigned short* wg  = wrz + WRZ_ELEMS;             // 256 KB

    prep_weights<<<192, 256, 0, stream>>>(wr, wz, whh, whx, wrz, wg);
    gru_fused<<<B_TOT / MT, 512, 0, stream>>>(x, h, wrz, wg, br, bz, bh, out);
}

// Round 6
// 144.870 us; speedup vs baseline: 1.4582x; 1.0772x over previous
//
#include <hip/hip_runtime.h>
#include <hip/hip_bf16.h>
#include <stdint.h>

// GRU cell, B=32768, IN=256, H=256, CONCAT=512. Fused bf16-MFMA kernel.
// R6 = R5 + __builtin_amdgcn_sched_barrier(0) fences between each group's
// B-prefetch loads and its MFMA block. R4/R5 post-mortem: the scheduler
// sank prefetch loads to their uses (VGPR_Count 92 proves buffers never
// lived), exposing ~300 cyc L2 latency per load group. The fence pins
// loads above MFMAs; waitcnt insertion (post-scheduling, per-register)
// then waits only on the OLDER group's loads (vmcnt(N), never 0).

typedef float  f32x4  __attribute__((ext_vector_type(4)));
typedef __bf16 bf16x8 __attribute__((ext_vector_type(8)));
typedef short  s16x8  __attribute__((ext_vector_type(8)));

#define B_TOT   32768
#define MT      64
#define WRZ_ELEMS (512*512)
#define WG_ELEMS  (256*512)

__device__ __forceinline__ unsigned short f2b(float f) {
    union { float f; unsigned int u; } v; v.f = f;
    unsigned int r = (v.u + 0x7FFFu + ((v.u >> 16) & 1u)) >> 16;  // RNE
    return (unsigned short)r;
}
__device__ __forceinline__ float b2f(unsigned short b) {
    union { unsigned int u; float f; } v; v.u = ((unsigned int)b) << 16;
    return v.f;
}
__device__ __forceinline__ ushort2 pk2(float a, float b) {   // v_cvt_pk_bf16_f32
    __hip_bfloat162 t = __float22bfloat162_rn(make_float2(a, b));
    union { __hip_bfloat162 h; ushort2 u; } c; c.h = t; return c.u;
}
__device__ __forceinline__ float sigmoid_f(float x) {
    return 1.0f / (1.0f + __expf(-x));
}
__device__ __forceinline__ float tanh_f(float x) {
    return 1.0f - 2.0f / (__expf(2.0f * x) + 1.0f);
}

// bf16 LDS tile 64x512 (64 KB), XOR-swizzled at 16B (8-elem) granularity.
__device__ __forceinline__ int lds_idx(int row, int col) {
    return row * 512 + ((((col >> 3) ^ (row & 7)) << 3) | (col & 7));
}

// ---------------------------------------------------------------------------
// Prep (unchanged from R4): fp32 -> bf16 ks-major per-wave fragment pages.
// wrz page (wave w): [ks 0..15][jn 0..3][512]; jn 0,1 r-cols, jn 2,3 z-cols.
// wg  page (wave w): [ks 0..15][j 0..1][512]; k<256 whx, k>=256 whh.
// ---------------------------------------------------------------------------
__global__ void prep_weights(const float* __restrict__ wr,
                             const float* __restrict__ wz,
                             const float* __restrict__ whh,
                             const float* __restrict__ whx,
                             unsigned short* __restrict__ wrz,
                             unsigned short* __restrict__ wg) {
    const int b = blockIdx.x;
    const int t = threadIdx.x;
    union { s16x8 v; unsigned short u[8]; } tmp;

    if (b < 128) {                       // wrz: block = (w, ks)
        int w = b >> 4, ks = b & 15;
        int jn = t >> 6, l = t & 63;
        int kbase = ks * 32 + ((l >> 4) << 3);
        int n = 32 * w + ((jn & 1) << 4) + (l & 15);
        const float* src = (jn < 2) ? wr : wz;
        #pragma unroll
        for (int jj = 0; jj < 8; ++jj)
            tmp.u[jj] = f2b(src[(kbase + jj) * 256 + n]);
        *reinterpret_cast<s16x8*>(wrz + (size_t)w * 32768 + ks * 2048 + t * 8) = tmp.v;
    } else {                             // wg: block = (w, ks-pair)
        int b2 = b - 128;
        int w = b2 >> 3, ksp = b2 & 7;
        int ksl = t >> 7, j = (t >> 6) & 1, l = t & 63;
        int ks = ksp * 2 + ksl;
        int kbase = ks * 32 + ((l >> 4) << 3);
        int n = 32 * w + (j << 4) + (l & 15);
        #pragma unroll
        for (int jj = 0; jj < 8; ++jj) {
            int k = kbase + jj;
            tmp.u[jj] = f2b((k < 256) ? whx[k * 256 + n] : whh[(k - 256) * 256 + n]);
        }
        *reinterpret_cast<s16x8*>(wg + (size_t)w * 16384 + ksp * 2048 + t * 8) = tmp.v;
    }
}

// ---------------------------------------------------------------------------
// Fused GRU: 512 threads (8 waves), 64 rows/block, grid 512.
// Wave w owns r/z/g cols [32w,32w+32). Main loop: 8 groups of 2 ks, B
// double-buffered with a sched_barrier(0) pinning prefetch loads above the
// MFMA block. Gates: a=sigmoid(r+br)*h -> x-region; h stashed in r-acc.
// Tail: 4 groups of 2 kt, same fencing. Epilogue: h + z*(tanh(g+bh)-h).
// ---------------------------------------------------------------------------
__global__ __launch_bounds__(512, 2)
void gru_fused(const float* __restrict__ x, const float* __restrict__ h,
               const unsigned short* __restrict__ wrz,
               const unsigned short* __restrict__ wg,
               const float* __restrict__ br, const float* __restrict__ bz,
               const float* __restrict__ bh, float* __restrict__ out) {
    __shared__ unsigned short xcA[64 * 512];   // 64 KB

    const int tid  = threadIdx.x;
    const int lane = tid & 63;
    const int wv   = tid >> 6;          // wave 0..7
    const int m0   = lane & 15;
    const int q    = lane >> 4;
    const int rowBase = blockIdx.x * MT;

    float brv[2], bzv[2], bhv[2];
    #pragma unroll
    for (int j = 0; j < 2; ++j) {
        int col = 32 * wv + j * 16 + m0;
        brv[j] = br[col]; bzv[j] = bz[col]; bhv[j] = bh[col];
    }

    // ---- Stage [x | h] -> LDS bf16 (packed HW cvt)
    #pragma unroll
    for (int it = 0; it < 8; ++it) {
        int row = it * 8 + wv;
        size_t g = (size_t)(rowBase + row) * 256 + lane * 4;
        float4 xv = *reinterpret_cast<const float4*>(x + g);
        float4 hv = *reinterpret_cast<const float4*>(h + g);
        ushort2 x0 = pk2(xv.x, xv.y), x1 = pk2(xv.z, xv.w);
        ushort2 h0 = pk2(hv.x, hv.y), h1 = pk2(hv.z, hv.w);
        ushort4 xb = make_ushort4(x0.x, x0.y, x1.x, x1.y);
        ushort4 hb = make_ushort4(h0.x, h0.y, h1.x, h1.y);
        *reinterpret_cast<ushort4*>(&xcA[lds_idx(row, lane * 4)])       = xb;
        *reinterpret_cast<ushort4*>(&xcA[lds_idx(row, 256 + lane * 4)]) = hb;
    }

    const unsigned short* wrzP = wrz + (size_t)wv * 32768;
    const unsigned short* wgP  = wg  + (size_t)wv * 16384;

    // ---- Preload B group 0 (ks 0,1: 4 rz + 2 g frags per ks)
    s16x8 Bb[2][12];
    #pragma unroll
    for (int k2 = 0; k2 < 2; ++k2) {
        #pragma unroll
        for (int jn = 0; jn < 4; ++jn)
            Bb[0][k2 * 6 + jn] = *reinterpret_cast<const s16x8*>(
                wrzP + k2 * 2048 + jn * 512 + lane * 8);
        #pragma unroll
        for (int j = 0; j < 2; ++j)
            Bb[0][k2 * 6 + 4 + j] = *reinterpret_cast<const s16x8*>(
                wgP + k2 * 1024 + j * 512 + lane * 8);
    }

    __syncthreads();

    f32x4 rz[4][4];     // jn 0,1 = r; jn 2,3 = z
    f32x4 gac[2][4];
    #pragma unroll
    for (int jn = 0; jn < 4; ++jn)
        #pragma unroll
        for (int mt = 0; mt < 4; ++mt)
            rz[jn][mt] = (f32x4){0.f, 0.f, 0.f, 0.f};
    #pragma unroll
    for (int j = 0; j < 2; ++j)
        #pragma unroll
        for (int mt = 0; mt < 4; ++mt)
            gac[j][mt] = (f32x4){0.f, 0.f, 0.f, 0.f};

    // ---- Main loop: 8 groups x 2 ks. grp<4: rz+g, grp>=4: rz only.
    #pragma unroll
    for (int grp = 0; grp < 8; ++grp) {
        const int cur = grp & 1, nxt = cur ^ 1;
        // Prefetch next group's B fragments (pinned above MFMAs by fence)
        if (grp < 7) {
            int gn = grp + 1;
            #pragma unroll
            for (int k2 = 0; k2 < 2; ++k2) {
                int ks = gn * 2 + k2;
                #pragma unroll
                for (int jn = 0; jn < 4; ++jn)
                    Bb[nxt][k2 * 6 + jn] = *reinterpret_cast<const s16x8*>(
                        wrzP + ks * 2048 + jn * 512 + lane * 8);
                if (gn < 4) {
                    #pragma unroll
                    for (int j = 0; j < 2; ++j)
                        Bb[nxt][k2 * 6 + 4 + j] = *reinterpret_cast<const s16x8*>(
                            wgP + ks * 1024 + j * 512 + lane * 8);
                }
            }
        }
        __builtin_amdgcn_sched_barrier(0);   // loads stay above, MFMAs below
        #pragma unroll
        for (int k2 = 0; k2 < 2; ++k2) {
            int ks = grp * 2 + k2;
            bf16x8 afr[4];
            #pragma unroll
            for (int mt = 0; mt < 4; ++mt) {
                int row = mt * 16 + m0;
                int idx = row * 512 + ((((ks << 2) | q) ^ (row & 7)) << 3);
                afr[mt] = __builtin_bit_cast(bf16x8,
                    *reinterpret_cast<const s16x8*>(&xcA[idx]));
            }
            #pragma unroll
            for (int jn = 0; jn < 4; ++jn) {
                bf16x8 bf = __builtin_bit_cast(bf16x8, Bb[cur][k2 * 6 + jn]);
                #pragma unroll
                for (int mt = 0; mt < 4; ++mt)
                    rz[jn][mt] = __builtin_amdgcn_mfma_f32_16x16x32_bf16(
                        afr[mt], bf, rz[jn][mt], 0, 0, 0);
            }
            if (grp < 4) {
                #pragma unroll
                for (int j = 0; j < 2; ++j) {
                    bf16x8 bf = __builtin_bit_cast(bf16x8, Bb[cur][k2 * 6 + 4 + j]);
                    #pragma unroll
                    for (int mt = 0; mt < 4; ++mt)
                        gac[j][mt] = __builtin_amdgcn_mfma_f32_16x16x32_bf16(
                            afr[mt], bf, gac[j][mt], 0, 0, 0);
                }
            }
        }
    }
    __syncthreads();   // all LDS A-reads done before x-region overwrite

    // ---- Preload tail group 0 (whh pages 8,9) — gates VALU hides latency
    s16x8 Tb[2][4];
    #pragma unroll
    for (int k2 = 0; k2 < 2; ++k2)
        #pragma unroll
        for (int j = 0; j < 2; ++j)
            Tb[0][k2 * 2 + j] = *reinterpret_cast<const s16x8*>(
                wgP + (8 + k2) * 1024 + j * 512 + lane * 8);

    // ---- Gates: a = sigmoid(r+br)*h -> LDS x-region; stash h in r-acc
    #pragma unroll
    for (int j = 0; j < 2; ++j) {
        int col = 32 * wv + j * 16 + m0;
        #pragma unroll
        for (int mt = 0; mt < 4; ++mt) {
            #pragma unroll
            for (int rg = 0; rg < 4; ++rg) {
                int row = mt * 16 + q * 4 + rg;
                float hval = b2f(xcA[lds_idx(row, 256 + col)]);
                float rs = sigmoid_f(rz[j][mt][rg] + brv[j]);
                xcA[lds_idx(row, col)] = f2b(rs * hval);
                rz[j][mt][rg] = hval;
            }
        }
    }
    __syncthreads();   // a visible to all waves

    // ---- Tail: g += a @ whh, 4 groups x 2 kt, double-buffered + fenced
    #pragma unroll
    for (int tg = 0; tg < 4; ++tg) {
        const int cur = tg & 1, nxt = cur ^ 1;
        if (tg < 3) {
            #pragma unroll
            for (int k2 = 0; k2 < 2; ++k2)
                #pragma unroll
                for (int j = 0; j < 2; ++j)
                    Tb[nxt][k2 * 2 + j] = *reinterpret_cast<const s16x8*>(
                        wgP + (10 + tg * 2 + k2) * 1024 + j * 512 + lane * 8);
        }
        __builtin_amdgcn_sched_barrier(0);
        #pragma unroll
        for (int k2 = 0; k2 < 2; ++k2) {
            int kt = tg * 2 + k2;
            bf16x8 afr[4];
            #pragma unroll
            for (int mt = 0; mt < 4; ++mt) {
                int row = mt * 16 + m0;
                int idx = row * 512 + ((((kt << 2) | q) ^ (row & 7)) << 3);
                afr[mt] = __builtin_bit_cast(bf16x8,
                    *reinterpret_cast<const s16x8*>(&xcA[idx]));
            }
            #pragma unroll
            for (int j = 0; j < 2; ++j) {
                bf16x8 bf = __builtin_bit_cast(bf16x8, Tb[cur][k2 * 2 + j]);
                #pragma unroll
                for (int mt = 0; mt < 4; ++mt)
                    gac[j][mt] = __builtin_amdgcn_mfma_f32_16x16x32_bf16(
                        afr[mt], bf, gac[j][mt], 0, 0, 0);
            }
        }
    }

    // ---- Epilogue: h_out = h + z*(tanh(g+bh) - h)
    #pragma unroll
    for (int j = 0; j < 2; ++j) {
        int col = 32 * wv + j * 16 + m0;
        #pragma unroll
        for (int mt = 0; mt < 4; ++mt) {
            #pragma unroll
            for (int rg = 0; rg < 4; ++rg) {
                int row = mt * 16 + q * 4 + rg;
                float zs = sigmoid_f(rz[2 + j][mt][rg] + bzv[j]);
                float gv = tanh_f(gac[j][mt][rg] + bhv[j]);
                float hval = rz[j][mt][rg];
                out[(size_t)(rowBase + row) * 256 + col] = hval + zs * (gv - hval);
            }
        }
    }
}

extern "C" void kernel_launch(void* const* d_in, const int* in_sizes, int n_in,
                              void* d_out, int out_size, void* d_ws, size_t ws_size,
                              hipStream_t stream) {
    const float* x   = (const float*)d_in[0];
    const float* h   = (const float*)d_in[1];
    const float* wr  = (const float*)d_in[2];
    const float* wz  = (const float*)d_in[3];
    const float* whh = (const float*)d_in[4];
    const float* whx = (const float*)d_in[5];
    const float* br  = (const float*)d_in[6];
    const float* bz  = (const float*)d_in[7];
    const float* bh  = (const float*)d_in[8];
    float* out = (float*)d_out;

    unsigned short* wrz = (unsigned short*)d_ws;       // 512 KB
    unsigned short* wg  = wrz + WRZ_ELEMS;             // 256 KB

    prep_weights<<<192, 256, 0, stream>>>(wr, wz, whh, whx, wrz, wg);
    gru_fused<<<B_TOT / MT, 512, 0, stream>>>(x, h, wrz, wg, br, bz, bh, out);
}